// Round 20
// baseline (1942.124 us; speedup 1.0000x reference)
//
#include <hip/hip_runtime.h>
#include <hip/hip_fp16.h>

#define N0C 200000
#define N1C 600000
#define N2C 400000
#define NRC (N0C + N1C + N2C)
#define NGC 128
#define D 32
#define CHUNKE 8192
#define BSHIFT 10
#define NBUK ((NRC + 1023) >> 10)   // 1172
#define ARENA_S 22528               // padded per-bucket: max-rank mean ~17.8K + >8 sigma
#define LDSE 15360

#define AB0 0
#define AB1 N0C
#define AB2 (N0C + N1C)
#define IMAXC 0x7fffffff

// XWbuf slot bases (layer-0 projections)
#define XB0 0
#define XB1 200000
#define XB2 800000
#define XB3 1200000
#define XB4 1600000
#define XB5 1800000
#define XB6 2400000

typedef __attribute__((ext_vector_type(8))) _Float16 half8;
typedef __attribute__((ext_vector_type(4))) float f32x4;
typedef unsigned long long u64;

struct BinArgs {
    const int* rows[7];
    const int* cols[7];
    const float* vals[7];
    int nnz[7];
    int cstart[8];
    int rbase[7];
    int cbase[7];
};

// ---------- init: cursor low32 = arena base, high32 = real count 0 ----------
__global__ void cursor_init_kernel(u64* __restrict__ cursor) {
    int b = blockIdx.x * blockDim.x + threadIdx.x;
    if (b < NBUK) cursor[b] = (u64)(unsigned)(b * ARENA_S);
}

// ---------- LDS-staged binning: full-line arena writes ----------
__global__ __launch_bounds__(256) void ubin_kernel(BinArgs A, u64* __restrict__ cursor,
                                                   int2* __restrict__ arena) {
    __shared__ int2 buf[CHUNKE];        // 64KB
    __shared__ int lofs[NBUK];          // LDS run starts
    __shared__ int lcur[NBUK];          // counts -> cursors -> run ends
    __shared__ int gbase[NBUK];         // reserved arena positions
    __shared__ int part[256];
    int tid = threadIdx.x;
    int bid = blockIdx.x;
    int m = 0;
    while (bid >= A.cstart[m + 1]) ++m;
    int base = (bid - A.cstart[m]) * CHUNKE;
    const int* rows = A.rows[m];
    const int* cols = A.cols[m];
    const float* vals = A.vals[m];
    int nnz = A.nnz[m];
    int rb = A.rbase[m];
    int cb = A.cbase[m];
    // P1: histogram into lcur
    for (int i = tid; i < NBUK; i += 256) lcur[i] = 0;
    __syncthreads();
    for (int i = tid; i < CHUNKE; i += 256) {
        int e = base + i;
        if (e < nnz) atomicAdd(&lcur[(rows[e] + rb) >> BSHIFT], 1);
    }
    __syncthreads();
    // P2: block exclusive scan (5 buckets per thread) -> lofs
    int v[5];
    {
        int s = 0;
#pragma unroll
        for (int u = 0; u < 5; ++u) {
            int b = tid * 5 + u;
            int c = (b < NBUK) ? lcur[b] : 0;
            v[u] = s;
            s += c;
        }
        part[tid] = s;
    }
    __syncthreads();
    if (tid == 0) {
        int acc = 0;
        for (int i = 0; i < 256; ++i) { int q = part[i]; part[i] = acc; acc += q; }
    }
    __syncthreads();
#pragma unroll
    for (int u = 0; u < 5; ++u) {
        int b = tid * 5 + u;
        if (b < NBUK) lofs[b] = part[tid] + v[u];
    }
    __syncthreads();
    // P3: reserve padded arena ranges; one packed 64-bit atomic per bucket
    for (int b = tid; b < NBUK; b += 256) {
        int c = lcur[b];
        if (c) {
            int pad = (c + 7) & ~7;
            u64 old = atomicAdd(&cursor[b], ((u64)(unsigned)c << 32) | (unsigned)pad);
            gbase[b] = (int)(unsigned)old;
        }
    }
    __syncthreads();
    // P4: reset cursors to run starts, scatter edges into LDS buffer
    for (int b = tid; b < NBUK; b += 256) lcur[b] = lofs[b];
    __syncthreads();
    for (int i = tid; i < CHUNKE; i += 256) {
        int e = base + i;
        if (e < nnz) {
            int r = rows[e] + rb;
            int b = r >> BSHIFT;
            int rl = r & ((1 << BSHIFT) - 1);
            int pos = atomicAdd(&lcur[b], 1);
            buf[pos] = make_int2((rl << 22) | (cols[e] + cb), __float_as_int(vals[e]));
        }
    }
    __syncthreads();
    // P5: coalesced full-line write-out per bucket run (+ sentinel tail)
    int wid = tid >> 6;
    int lane = tid & 63;
    for (int b = wid; b < NBUK; b += 4) {
        int start = lofs[b];
        int len = lcur[b] - start;
        if (!len) continue;
        int pad = (len + 7) & ~7;
        int g = gbase[b];
        for (int i = lane; i < pad; i += 64)
            arena[g + i] = (i < len) ? buf[start + i] : make_int2(-1, 0);
    }
}

// ---------- exclusive scan of REAL counts (cursor high32) -> cvbase ----------
__global__ __launch_bounds__(256) void scan_counts_kernel(const u64* __restrict__ cursor,
                                                          int* __restrict__ cvbase) {
    __shared__ int part[256];
    int t = threadIdx.x;
    int s = 0;
    int v[8];
#pragma unroll
    for (int u = 0; u < 8; ++u) {
        int b = t * 8 + u;
        int c = (b < NBUK) ? (int)(cursor[b] >> 32) : 0;
        v[u] = s;
        s += c;
    }
    part[t] = s;
    __syncthreads();
    if (t == 0) {
        int acc = 0;
        for (int i = 0; i < 256; ++i) { int q = part[i]; part[i] = acc; acc += q; }
    }
    __syncthreads();
    int off = part[t];
#pragma unroll
    for (int u = 0; u < 8; ++u) {
        int b = t * 8 + u;
        if (b <= NBUK) cvbase[b] = off + v[u];
    }
    if (t == 255) cvbase[NBUK] = off + s;
}

__global__ void set_final_kernel(int* __restrict__ dst, int v) { *dst = v; }

// ---------- per-bucket sort: compact-load (skip sentinels) + LDS counting sort ----------
__global__ __launch_bounds__(256) void binsort_kernel(const int2* __restrict__ arena,
                                                      const u64* __restrict__ cursor,
                                                      const int* __restrict__ cvbase,
                                                      int* __restrict__ rowptr,
                                                      int2* __restrict__ cv, int nrows) {
    __shared__ int hcnt[1024], sa[1024], sb[1024], rcur[1024];
    __shared__ int2 buf[LDSE];
    __shared__ int nload;
    int b = blockIdx.x;
    int cntp = (int)(unsigned)cursor[b] - b * ARENA_S;   // padded count
    int cntreal = (int)(cursor[b] >> 32);
    int cvb = cvbase[b];
    const int2* stage = arena + (size_t)b * ARENA_S;
    int nr = 1 << BSHIFT;
    int rb = b << BSHIFT;
    for (int i = threadIdx.x; i < nr; i += 256) hcnt[i] = 0;
    if (threadIdx.x == 0) nload = 0;
    __syncthreads();
    bool fits = (cntreal <= LDSE);
    if (fits) {
        for (int i = threadIdx.x; i < cntp; i += 256) {
            int2 e = stage[i];
            if (e.x != -1) {
                int p = atomicAdd(&nload, 1);
                buf[p] = e;
                atomicAdd(&hcnt[(unsigned)e.x >> 22], 1);
            }
        }
    } else {
        for (int i = threadIdx.x; i < cntp; i += 256) {
            int2 e = stage[i];
            if (e.x != -1) atomicAdd(&hcnt[(unsigned)e.x >> 22], 1);
        }
    }
    __syncthreads();
    for (int i = threadIdx.x; i < nr; i += 256) sa[i] = hcnt[i];
    __syncthreads();
    int* curp = sa; int* nxtp = sb;
    for (int off = 1; off < nr; off <<= 1) {
        for (int i = threadIdx.x; i < nr; i += 256)
            nxtp[i] = (i >= off) ? curp[i - off] + curp[i] : curp[i];
        __syncthreads();
        int* t = curp; curp = nxtp; nxtp = t;
    }
    for (int i = threadIdx.x; i < nr; i += 256) {
        int excl = curp[i] - hcnt[i];
        rcur[i] = excl;
        int row = rb + i;
        if (row < nrows) rowptr[row] = cvb + excl;
    }
    __syncthreads();
    if (fits) {
        for (int i = threadIdx.x; i < cntreal; i += 256) {
            int2 e = buf[i];
            int rl = (unsigned)e.x >> 22;
            int pos = atomicAdd(&rcur[rl], 1);
            cv[cvb + pos] = make_int2(e.x & 0x3FFFFF, e.y);
        }
    } else {
        for (int i = threadIdx.x; i < cntp; i += 256) {
            int2 e = stage[i];
            if (e.x != -1) {
                int rl = (unsigned)e.x >> 22;
                int pos = atomicAdd(&rcur[rl], 1);
                cv[cvb + pos] = make_int2(e.x & 0x3FFFFF, e.y);
            }
        }
    }
}

// ---------- fused MFMA projection (layer 0, DIN=64, fp32 src) ----------
template <int NM>
__global__ __launch_bounds__(256) void xw_fused_kernel(
    const float* __restrict__ xsrc,
    const float* __restrict__ Wa, const float* __restrict__ Wb, const float* __restrict__ Wc,
    __half* __restrict__ oa, __half* __restrict__ ob, __half* __restrict__ oc, int n) {
    int wave = (blockIdx.x * 256 + threadIdx.x) >> 6;
    int lane = threadIdx.x & 63;
    int nwaves = (gridDim.x * 256) >> 6;
    int li = lane & 15;
    int lk = lane >> 4;
    const float* Ws[3] = { Wa, Wb, Wc };
    __half* Os[3] = { oa, ob, oc };
    half8 bfrag[NM][2][2];
#pragma unroll
    for (int m = 0; m < NM; ++m)
#pragma unroll
        for (int ct = 0; ct < 2; ++ct)
#pragma unroll
            for (int ks = 0; ks < 2; ++ks)
#pragma unroll
                for (int r = 0; r < 8; ++r) {
                    int k = ks * 32 + lk * 8 + r;
                    int j = ct * 16 + li;
                    bfrag[m][ct][ks][r] = (_Float16)Ws[m][k * 32 + j];
                }
    int ntiles = (n + 15) >> 4;
    for (int t = wave; t < ntiles; t += nwaves) {
        int rbase = t << 4;
        int arow = rbase + li;
        int arowc = (arow < n) ? arow : (n - 1);
        half8 afrag[2];
#pragma unroll
        for (int ks = 0; ks < 2; ++ks) {
            const float* p = xsrc + (size_t)arowc * 64 + ks * 32 + lk * 8;
            float4 u = *(const float4*)p;
            float4 v = *(const float4*)(p + 4);
            afrag[ks] = (half8){ (_Float16)u.x, (_Float16)u.y, (_Float16)u.z, (_Float16)u.w,
                                 (_Float16)v.x, (_Float16)v.y, (_Float16)v.z, (_Float16)v.w };
        }
#pragma unroll
        for (int m = 0; m < NM; ++m) {
#pragma unroll
            for (int ct = 0; ct < 2; ++ct) {
                f32x4 acc = { 0.f, 0.f, 0.f, 0.f };
#pragma unroll
                for (int ks = 0; ks < 2; ++ks)
                    acc = __builtin_amdgcn_mfma_f32_16x16x32_f16(afrag[ks], bfrag[m][ct][ks],
                                                                 acc, 0, 0, 0);
#pragma unroll
                for (int r = 0; r < 4; ++r) {
                    int row = rbase + lk * 4 + r;
                    if (row < n)
                        Os[m][(size_t)row * 32 + ct * 16 + li] = __float2half(acc[r]);
                }
            }
        }
    }
}

// ---------- layer-0 unified gather (act cols -> XWbuf slots) ----------
// no min-waves clause (round-10: forcing 8 waves/SIMD spills q[8] -> scratch traffic)
__global__ __launch_bounds__(256) void gather0_kernel(
    const int* __restrict__ rp, const int2* __restrict__ cv,
    const __half* __restrict__ XW, __half* __restrict__ act, int nrows) {
    int row = (blockIdx.x * 256 + threadIdx.x) >> 2;
    int j = threadIdx.x & 3;
    if (row >= nrows) return;
    int rank = (row >= AB2) ? 2 : ((row >= AB1) ? 1 : 0);
    int t1 = (rank == 2) ? AB2 : AB1;
    int t2 = (rank == 1) ? AB2 : IMAXC;
    int off0 = (rank == 0) ? (XB0 - AB0) : ((rank == 1) ? (XB4 - AB0) : (XB6 - AB1));
    int off1 = (rank == 0) ? (XB5 - AB1) : ((rank == 1) ? (XB1 - AB1) : (XB2 - AB2));
    int off2 = (rank == 1) ? (XB3 - AB2) : 0;
    float scale = (rank == 1) ? (1.f / 3.f) : 0.5f;
    int ks = rp[row], ke = rp[row + 1];
    float s[8] = { 0.f, 0.f, 0.f, 0.f, 0.f, 0.f, 0.f, 0.f };
    for (int k = ks; k < ke; k += 8) {
        int2 e[8];
#pragma unroll
        for (int u = 0; u < 8; ++u) {
            int kk = k + u;
            e[u] = cv[(kk < ke) ? kk : (ke - 1)];
        }
        uint4 q[8];
#pragma unroll
        for (int u = 0; u < 8; ++u) {
            int c = e[u].x;
            int add = (c < t1) ? off0 : ((c < t2) ? off1 : off2);
            q[u] = *(const uint4*)(XW + (size_t)(c + add) * 32 + j * 8);
        }
#pragma unroll
        for (int u = 0; u < 8; ++u) {
            float v = (k + u < ke) ? __int_as_float(e[u].y) : 0.f;
            const unsigned* qq = &q[u].x;
#pragma unroll
            for (int h = 0; h < 4; ++h) {
                float2 f2 = __half22float2(*(__half2*)&qq[h]);
                s[2 * h] = fmaf(v, f2.x, s[2 * h]);
                s[2 * h + 1] = fmaf(v, f2.y, s[2 * h + 1]);
            }
        }
    }
    uint4 ov;
    unsigned* op = &ov.x;
#pragma unroll
    for (int h = 0; h < 4; ++h) {
        __half2 o2 = __floats2half2_rn(fmaxf(s[2 * h], 0.f) * scale,
                                       fmaxf(s[2 * h + 1], 0.f) * scale);
        op[h] = *(unsigned*)&o2;
    }
    *(uint4*)(act + (size_t)row * 32 + j * 8) = ov;
}

// ---------- layers 1..3 unified fused gather+W ----------
__global__ __launch_bounds__(256) void ugw_kernel(
    const int* __restrict__ rp, const int2* __restrict__ cv,
    const __half* __restrict__ actin, __half* __restrict__ actout,
    const float* __restrict__ Wl, int tile0, int ntiles) {
    int gid = (blockIdx.x * 256 + threadIdx.x) >> 6;
    if (gid >= ntiles) return;
    gid += tile0;
    int lane = threadIdx.x & 63;
    int li = lane & 15;
    int lk = lane >> 4;
    int rbase = gid << 4;
    int rank = (rbase >= AB2) ? 2 : ((rbase >= AB1) ? 1 : 0);
    int t1 = (rank == 2) ? AB2 : AB1;
    int t2 = (rank == 1) ? AB2 : IMAXC;
    float scale = (rank == 1) ? (1.f / 3.f) : 0.5f;
    int wk0 = (rank == 0) ? 0 : ((rank == 1) ? 1 : 4);
    int wk1 = (rank == 0) ? 3 : ((rank == 1) ? 2 : 6);
    int wk2 = (rank == 1) ? 5 : 0;
    const float* Wa = Wl + (size_t)wk0 * 1024;
    const float* Wb = Wl + (size_t)wk1 * 1024;
    const float* Wc = Wl + (size_t)wk2 * 1024;
    int row = rbase + li;
    int ks = rp[row], ke = rp[row + 1];
    float acc[3][8];
#pragma unroll
    for (int m = 0; m < 3; ++m)
#pragma unroll
        for (int d = 0; d < 8; ++d) acc[m][d] = 0.f;
    for (int k = ks; k < ke; k += 8) {
        int2 e[8];
#pragma unroll
        for (int u = 0; u < 8; ++u) {
            int kk = k + u;
            e[u] = cv[(kk < ke) ? kk : (ke - 1)];
        }
        uint4 q[8];
#pragma unroll
        for (int u = 0; u < 8; ++u)
            q[u] = *(const uint4*)(actin + (size_t)e[u].x * 32 + lk * 8);
#pragma unroll
        for (int u = 0; u < 8; ++u) {
            float bv = (k + u < ke) ? __int_as_float(e[u].y) : 0.f;
            int c = e[u].x;
            float s0 = (c < t1) ? bv : 0.f;
            float s2 = (c >= t2) ? bv : 0.f;
            float s1 = bv - s0 - s2;
            const unsigned* qq = &q[u].x;
#pragma unroll
            for (int h = 0; h < 4; ++h) {
                float2 f2 = __half22float2(*(__half2*)&qq[h]);
                acc[0][2 * h] = fmaf(s0, f2.x, acc[0][2 * h]);
                acc[0][2 * h + 1] = fmaf(s0, f2.y, acc[0][2 * h + 1]);
                acc[1][2 * h] = fmaf(s1, f2.x, acc[1][2 * h]);
                acc[1][2 * h + 1] = fmaf(s1, f2.y, acc[1][2 * h + 1]);
                acc[2][2 * h] = fmaf(s2, f2.x, acc[2][2 * h]);
                acc[2][2 * h + 1] = fmaf(s2, f2.y, acc[2][2 * h + 1]);
            }
        }
    }
    const float* Ws[3] = { Wa, Wb, Wc };
    f32x4 d0 = { 0.f, 0.f, 0.f, 0.f };
    f32x4 d1 = { 0.f, 0.f, 0.f, 0.f };
#pragma unroll
    for (int m = 0; m < 3; ++m) {
        half8 a, b0, b1;
#pragma unroll
        for (int r = 0; r < 8; ++r) {
            a[r] = (_Float16)acc[m][r];
            int kk = lk * 8 + r;
            b0[r] = (_Float16)Ws[m][kk * 32 + li];
            b1[r] = (_Float16)Ws[m][kk * 32 + 16 + li];
        }
        d0 = __builtin_amdgcn_mfma_f32_16x16x32_f16(a, b0, d0, 0, 0, 0);
        d1 = __builtin_amdgcn_mfma_f32_16x16x32_f16(a, b1, d1, 0, 0, 0);
    }
#pragma unroll
    for (int r = 0; r < 4; ++r) {
        size_t orow = (size_t)(rbase + lk * 4 + r);
        actout[orow * 32 + li] = __float2half(fmaxf(d0[r], 0.f) * scale);
        actout[orow * 32 + 16 + li] = __float2half(fmaxf(d1[r], 0.f) * scale);
    }
}

// ---------- pooling ----------
#define BPG 4
__global__ __launch_bounds__(256) void pool_kernel(const __half* __restrict__ x1,
                                                   const int* __restrict__ batch,
                                                   float* __restrict__ sums,
                                                   float* __restrict__ cnt, int n) {
    __shared__ float red[256][8];
    int g = blockIdx.x / BPG;
    int p = blockIdx.x % BPG;
    int lo = 0, hi = n;
    while (lo < hi) { int mid = (lo + hi) >> 1; if (batch[mid] < g) lo = mid + 1; else hi = mid; }
    int s0 = lo;
    lo = s0; hi = n;
    while (lo < hi) { int mid = (lo + hi) >> 1; if (batch[mid] < g + 1) lo = mid + 1; else hi = mid; }
    int s1 = lo;
    int tid = threadIdx.x;
    int qr = tid & 3;
    int rt = tid >> 2;
    float acc[8] = { 0.f, 0.f, 0.f, 0.f, 0.f, 0.f, 0.f, 0.f };
    for (int r = s0 + p * 64 + rt; r < s1; r += BPG * 64) {
        half8 v = *(const half8*)(x1 + (size_t)r * 32 + qr * 8);
#pragma unroll
        for (int u = 0; u < 8; ++u) acc[u] += fabsf((float)v[u]);
    }
#pragma unroll
    for (int u = 0; u < 8; ++u) red[tid][u] = acc[u];
    __syncthreads();
    for (int off = 128; off >= 4; off >>= 1) {
        if (tid < off) {
#pragma unroll
            for (int u = 0; u < 8; ++u) red[tid][u] += red[tid + off][u];
        }
        __syncthreads();
    }
    if (tid < 4) {
#pragma unroll
        for (int u = 0; u < 8; ++u)
            atomicAdd(&sums[(size_t)g * D + tid * 8 + u], red[tid][u]);
    }
    if (p == 0 && tid == 0) cnt[g] = (float)(s1 - s0);
}

// ---------- head ----------
__global__ void head_kernel(const float* __restrict__ sums, const float* __restrict__ cnt,
                            const float* __restrict__ w1, const float* __restrict__ b1,
                            const float* __restrict__ w2, const float* __restrict__ b2,
                            float* __restrict__ out) {
    __shared__ float W1s[D * D], W2s[D * 10], B1s[D], B2s[10];
    int tid = threadIdx.x;
    for (int i = tid; i < D * D; i += blockDim.x) W1s[i] = w1[i];
    for (int i = tid; i < D * 10; i += blockDim.x) W2s[i] = w2[i];
    if (tid < D) B1s[tid] = b1[tid];
    if (tid < 10) B2s[tid] = b2[tid];
    __syncthreads();
    int g = tid;
    if (g >= NGC) return;
    float invc = 1.f / fmaxf(cnt[g], 1.f);
    float p[D];
#pragma unroll
    for (int k = 0; k < D; ++k) p[k] = sums[(size_t)g * D + k] * invc;
    float h[D];
#pragma unroll
    for (int j = 0; j < D; ++j) {
        float s = B1s[j];
#pragma unroll
        for (int k = 0; k < D; ++k) s = fmaf(p[k], W1s[k * D + j], s);
        h[j] = fmaxf(s, 0.f);
    }
    float l[10];
    float m = -1e30f;
#pragma unroll
    for (int o = 0; o < 10; ++o) {
        float s = B2s[o];
#pragma unroll
        for (int k = 0; k < D; ++k) s = fmaf(h[k], W2s[k * 10 + o], s);
        l[o] = s;
        m = fmaxf(m, s);
    }
    float den = 0.f;
#pragma unroll
    for (int o = 0; o < 10; ++o) { l[o] = expf(l[o] - m); den += l[o]; }
    float inv = 1.f / den;
#pragma unroll
    for (int o = 0; o < 10; ++o) out[g * 10 + o] = l[o] * inv;
}

extern "C" void kernel_launch(void* const* d_in, const int* in_sizes, int n_in,
                              void* d_out, int out_size, void* d_ws, size_t ws_size,
                              hipStream_t stream) {
    const float* X0 = (const float*)d_in[0];
    const float* X1 = (const float*)d_in[1];
    const float* X2 = (const float*)d_in[2];
    // mats: 0=L0,1=L1,2=L2,3=B2D3,4=D2B1TD1inv,5=D1invB1,6=B2TD2inv
    const int* spr[7]; const int* spc[7]; const float* spv[7]; int spn[7];
    for (int m = 0; m < 7; ++m) {
        spr[m] = (const int*)d_in[3 + m * 3];
        spc[m] = (const int*)d_in[4 + m * 3];
        spv[m] = (const float*)d_in[5 + m * 3];
        spn[m] = in_sizes[3 + m * 3];
    }
    const int* batch1 = (const int*)d_in[24];
    const float* W1 = (const float*)d_in[25];
    const float* W234 = (const float*)d_in[26];
    const float* mlp1_w = (const float*)d_in[27];
    const float* mlp1_b = (const float*)d_in[28];
    const float* mlp2_w = (const float*)d_in[29];
    const float* mlp2_b = (const float*)d_in[30];
    float* out = (float*)d_out;

    const int rowbase_mat[7] = { AB0, AB1, AB2, AB1, AB1, AB0, AB2 };
    const int colbase_mat[7] = { AB0, AB1, AB2, AB2, AB0, AB1, AB1 };
    const int XWROWS = 3000000;

    // ---- workspace carve (every allocation 64B-aligned; u64 atomics REQUIRE >=8B) ----
#define ALIGN64(p) ((char*)(((size_t)(p) + 63) & ~(size_t)63))
    char* wp = (char*)d_ws;
    __half* actA = (__half*)wp;            wp = ALIGN64(wp + (size_t)NRC * 32 * sizeof(__half));
    __half* XWbuf = (__half*)wp;           wp = ALIGN64(wp + (size_t)XWROWS * 32 * sizeof(__half));
    __half* actB = XWbuf;                  // aliases XWbuf (XWbuf dead after gather0)
    size_t total_nnz = 0;
    for (int m = 0; m < 7; ++m) total_nnz += (size_t)spn[m];
    int2* cv_base = (int2*)wp;             wp = ALIGN64(wp + total_nnz * sizeof(int2));
    int* rowptr = (int*)wp;                wp = ALIGN64(wp + (size_t)(NRC + 3) * sizeof(int));
    u64* cursor = (u64*)wp;                wp = ALIGN64(wp + (size_t)(NBUK + 4) * sizeof(u64));
    int* cvbase = (int*)wp;                wp = ALIGN64(wp + (size_t)(NBUK + 4) * sizeof(int));
    float* sums = (float*)wp;              wp = ALIGN64(wp + (size_t)NGC * D * sizeof(float));
    float* cnt = (float*)wp;               wp = ALIGN64(wp + (size_t)NGC * sizeof(float));
#undef ALIGN64

    // arena aliases [actA..XWbuf): 268.8MB available, need 1172*22528*8 = 211.2MB.
    // XWbuf slots written only AFTER binsort consumed the arena.
    int2* arena = (int2*)actA;

    // ---- build: LDS-staged binning -> scan -> sort ----
    int ncht = 0;
    {
        BinArgs A;
        for (int m = 0; m < 7; ++m) {
            A.rows[m] = spr[m];
            A.cols[m] = spc[m];
            A.vals[m] = spv[m];
            A.nnz[m] = spn[m];
            A.rbase[m] = rowbase_mat[m];
            A.cbase[m] = colbase_mat[m];
            A.cstart[m] = ncht;
            ncht += (spn[m] + CHUNKE - 1) / CHUNKE;
        }
        A.cstart[7] = ncht;
        cursor_init_kernel<<<(NBUK + 255) / 256, 256, 0, stream>>>(cursor);
        ubin_kernel<<<ncht, 256, 0, stream>>>(A, cursor, arena);
        scan_counts_kernel<<<1, 256, 0, stream>>>(cursor, cvbase);
        binsort_kernel<<<NBUK, 256, 0, stream>>>(arena, cursor, cvbase, rowptr,
                                                 cv_base, NRC);
        set_final_kernel<<<1, 1, 0, stream>>>(rowptr + NRC, (int)total_nnz);
    }

    // ---- layer 0: 3 fused xw (after binsort frees the arena alias), then gather ----
    {
        const size_t wst = (size_t)64 * 32;
        xw_fused_kernel<2><<<2048, 256, 0, stream>>>(
            X0, W1 + 0 * wst, W1 + 1 * wst, nullptr,
            XWbuf + (size_t)XB0 * 32, XWbuf + (size_t)XB4 * 32, nullptr, N0C);
        xw_fused_kernel<3><<<2048, 256, 0, stream>>>(
            X1, W1 + 2 * wst, W1 + 3 * wst, W1 + 4 * wst,
            XWbuf + (size_t)XB1 * 32, XWbuf + (size_t)XB5 * 32,
            XWbuf + (size_t)XB6 * 32, N1C);
        xw_fused_kernel<2><<<2048, 256, 0, stream>>>(
            X2, W1 + 6 * wst, W1 + 5 * wst, nullptr,
            XWbuf + (size_t)XB2 * 32, XWbuf + (size_t)XB3 * 32, nullptr, N2C);
        gather0_kernel<<<(int)(((size_t)NRC * 4 + 255) / 256), 256, 0, stream>>>(
            rowptr, cv_base, XWbuf, actA, NRC);
    }

    // ---- layers 1..3: one unified gather+W dispatch each ----
    for (int l = 1; l < 4; ++l) {
        const float* Wl = W234 + (size_t)(l - 1) * 7 * 32 * 32;
        const __half* src = (l & 1) ? actA : actB;
        __half* dst = (l & 1) ? actB : actA;
        if (l < 3) {
            int ntiles = NRC / 16;
            ugw_kernel<<<(ntiles + 3) / 4, 256, 0, stream>>>(
                rowptr, cv_base, src, dst, Wl, 0, ntiles);
        } else {
            int ntiles = N1C / 16;
            ugw_kernel<<<(ntiles + 3) / 4, 256, 0, stream>>>(
                rowptr, cv_base, src, dst, Wl, AB1 / 16, ntiles);
        }
    }

    hipMemsetAsync(sums, 0, (size_t)(NGC * D + NGC) * sizeof(float), stream);
    pool_kernel<<<NGC * BPG, 256, 0, stream>>>(actB + (size_t)AB1 * 32, batch1, sums, cnt, N1C);
    head_kernel<<<1, 128, 0, stream>>>(sums, cnt, mlp1_w, mlp1_b, mlp2_w, mlp2_b, out);
}

// Round 22
// 1839.809 us; speedup vs baseline: 1.0556x; 1.0556x over previous
//
#include <hip/hip_runtime.h>
#include <hip/hip_fp16.h>

#define N0C 200000
#define N1C 600000
#define N2C 400000
#define NRC (N0C + N1C + N2C)
#define NGC 128
#define D 32
#define CHUNKE 8192
#define BSHIFT 10
#define NBUK ((NRC + 1023) >> 10)   // 1172
#define ARENA_S 15488               // exact counts: mean 14334 + ~9.6 sigma (no padding)
#define LDSE 15360
#define GXW 2048

#define AB0 0
#define AB1 N0C
#define AB2 (N0C + N1C)
#define IMAXC 0x7fffffff

#define XB0 0
#define XB1 200000
#define XB2 800000
#define XB3 1200000
#define XB4 1600000
#define XB5 1800000
#define XB6 2400000

typedef __attribute__((ext_vector_type(8))) _Float16 half8;
typedef __attribute__((ext_vector_type(4))) float f32x4;
typedef unsigned long long u64;

struct BuildArgs {
    const int* rows[7];
    const int* cols[7];
    const float* vals[7];
    int nnz[7];
    int cstart[8];
    int rbase[7];
    int cbase[7];
    int ncht;
    const float* xs[3];
    const float* Wp[9];
    __half* Op[9];
    int nS[3];
    int nmS[3];
    int xb0[3];
    int xnb[3];
};

// ---------- init: cursor low32 = arena base, high32 = real count 0 ----------
__global__ void cursor_init_kernel(u64* __restrict__ cursor) {
    int b = blockIdx.x * blockDim.x + threadIdx.x;
    if (b < NBUK) cursor[b] = (u64)(unsigned)(b * ARENA_S);
}

// ---------- fused: [0,ncht) LDS-staged bin blocks ; [ncht,ncht+GXW) layer-0 xw ----------
__global__ __launch_bounds__(256) void ubin_xw_kernel(BuildArgs A, u64* __restrict__ cursor,
                                                      int2* __restrict__ arena) {
    __shared__ int2 buf[CHUNKE];        // 64KB
    __shared__ int lofs[NBUK];
    __shared__ int lcur[NBUK];
    __shared__ int gbase[NBUK];
    __shared__ int part[256];
    int tid = threadIdx.x;
    int bid = blockIdx.x;
    if (bid < A.ncht) {
        int m = 0;
        while (bid >= A.cstart[m + 1]) ++m;
        int base = (bid - A.cstart[m]) * CHUNKE;
        const int* rows = A.rows[m];
        const int* cols = A.cols[m];
        const float* vals = A.vals[m];
        int nnz = A.nnz[m];
        int rb = A.rbase[m];
        int cb = A.cbase[m];
        // P1: histogram
        for (int i = tid; i < NBUK; i += 256) lcur[i] = 0;
        __syncthreads();
        for (int i = tid; i < CHUNKE; i += 256) {
            int e = base + i;
            if (e < nnz) atomicAdd(&lcur[(rows[e] + rb) >> BSHIFT], 1);
        }
        __syncthreads();
        // P2: block exclusive scan -> lofs
        int v[5];
        {
            int s = 0;
#pragma unroll
            for (int u = 0; u < 5; ++u) {
                int b = tid * 5 + u;
                int c = (b < NBUK) ? lcur[b] : 0;
                v[u] = s;
                s += c;
            }
            part[tid] = s;
        }
        __syncthreads();
        if (tid == 0) {
            int acc = 0;
            for (int i = 0; i < 256; ++i) { int q = part[i]; part[i] = acc; acc += q; }
        }
        __syncthreads();
#pragma unroll
        for (int u = 0; u < 5; ++u) {
            int b = tid * 5 + u;
            if (b < NBUK) lofs[b] = part[tid] + v[u];
        }
        __syncthreads();
        // P3: reserve EXACT arena ranges (packed u64 atomic; low=pos, high=count)
        for (int b = tid; b < NBUK; b += 256) {
            int c = lcur[b];
            if (c) {
                u64 old = atomicAdd(&cursor[b], ((u64)(unsigned)c << 32) | (unsigned)c);
                gbase[b] = (int)(unsigned)old;
            }
        }
        __syncthreads();
        // P4: scatter edges into LDS buffer bucket-ordered
        for (int b = tid; b < NBUK; b += 256) lcur[b] = lofs[b];
        __syncthreads();
        for (int i = tid; i < CHUNKE; i += 256) {
            int e = base + i;
            if (e < nnz) {
                int r = rows[e] + rb;
                int b = r >> BSHIFT;
                int rl = r & ((1 << BSHIFT) - 1);
                int pos = atomicAdd(&lcur[b], 1);
                buf[pos] = make_int2((rl << 22) | (cols[e] + cb), __float_as_int(vals[e]));
            }
        }
        __syncthreads();
        // P5: coalesced burst write-out per bucket run (exact length)
        int wid = tid >> 6;
        int lane = tid & 63;
        for (int b = wid; b < NBUK; b += 4) {
            int start = lofs[b];
            int len = lcur[b] - start;
            if (!len) continue;
            int g = gbase[b];
            for (int i = lane; i < len; i += 64)
                arena[g + i] = buf[start + i];
        }
        return;
    }
    // ---------------- layer-0 xw path (DIN=64, fp32 src; no LDS use) ----------------
    int xwid = bid - A.ncht;
    int s = (xwid >= A.xb0[2]) ? 2 : ((xwid >= A.xb0[1]) ? 1 : 0);
    int tbase = xwid - A.xb0[s];
    int tstride = A.xnb[s];
    const float* xsrc = A.xs[s];
    int n = A.nS[s];
    int nm = A.nmS[s];
    const float* W0 = A.Wp[s * 3 + 0];
    const float* W1p = A.Wp[s * 3 + 1];
    const float* W2p = (nm > 2) ? A.Wp[s * 3 + 2] : A.Wp[s * 3 + 0];
    __half* O0 = A.Op[s * 3 + 0];
    __half* O1 = A.Op[s * 3 + 1];
    __half* O2 = (nm > 2) ? A.Op[s * 3 + 2] : nullptr;
    const float* Ws[3] = { W0, W1p, W2p };
    __half* Os[3] = { O0, O1, O2 };

    int wave = (tbase * 256 + tid) >> 6;
    int nwaves = tstride * 4;
    int lane = tid & 63;
    int li = lane & 15;
    int lk = lane >> 4;
    half8 bfrag[3][2][2];
#pragma unroll
    for (int m = 0; m < 3; ++m)
#pragma unroll
        for (int ct = 0; ct < 2; ++ct)
#pragma unroll
            for (int ks = 0; ks < 2; ++ks)
#pragma unroll
                for (int r = 0; r < 8; ++r) {
                    int k = ks * 32 + lk * 8 + r;
                    int j = ct * 16 + li;
                    bfrag[m][ct][ks][r] = (_Float16)Ws[m][k * 32 + j];
                }
    int ntiles = (n + 15) >> 4;
    for (int t = wave; t < ntiles; t += nwaves) {
        int rbase = t << 4;
        int arow = rbase + li;
        int arowc = (arow < n) ? arow : (n - 1);
        half8 afrag[2];
#pragma unroll
        for (int ks = 0; ks < 2; ++ks) {
            const float* p = xsrc + (size_t)arowc * 64 + ks * 32 + lk * 8;
            float4 u = *(const float4*)p;
            float4 v = *(const float4*)(p + 4);
            afrag[ks] = (half8){ (_Float16)u.x, (_Float16)u.y, (_Float16)u.z, (_Float16)u.w,
                                 (_Float16)v.x, (_Float16)v.y, (_Float16)v.z, (_Float16)v.w };
        }
#pragma unroll
        for (int m = 0; m < 3; ++m) {
            if (!Os[m]) continue;
#pragma unroll
            for (int ct = 0; ct < 2; ++ct) {
                f32x4 acc = { 0.f, 0.f, 0.f, 0.f };
#pragma unroll
                for (int ks = 0; ks < 2; ++ks)
                    acc = __builtin_amdgcn_mfma_f32_16x16x32_f16(afrag[ks], bfrag[m][ct][ks],
                                                                 acc, 0, 0, 0);
#pragma unroll
                for (int r = 0; r < 4; ++r) {
                    int row = rbase + lk * 4 + r;
                    if (row < n)
                        Os[m][(size_t)row * 32 + ct * 16 + li] = __float2half(acc[r]);
                }
            }
        }
    }
}

// ---------- exclusive scan of real counts (cursor high32) -> cvbase ----------
__global__ __launch_bounds__(256) void scan_counts_kernel(const u64* __restrict__ cursor,
                                                          int* __restrict__ cvbase) {
    __shared__ int part[256];
    int t = threadIdx.x;
    int s = 0;
    int v[8];
#pragma unroll
    for (int u = 0; u < 8; ++u) {
        int b = t * 8 + u;
        int c = (b < NBUK) ? (int)(cursor[b] >> 32) : 0;
        v[u] = s;
        s += c;
    }
    part[t] = s;
    __syncthreads();
    if (t == 0) {
        int acc = 0;
        for (int i = 0; i < 256; ++i) { int q = part[i]; part[i] = acc; acc += q; }
    }
    __syncthreads();
    int off = part[t];
#pragma unroll
    for (int u = 0; u < 8; ++u) {
        int b = t * 8 + u;
        if (b <= NBUK) cvbase[b] = off + v[u];
    }
    if (t == 255) cvbase[NBUK] = off + s;
}

__global__ void set_final_kernel(int* __restrict__ dst, int v) { *dst = v; }

// ---------- per-bucket sort: straight load (no sentinels) + LDS counting sort ----------
__global__ __launch_bounds__(256) void binsort_kernel(const int2* __restrict__ arena,
                                                      const u64* __restrict__ cursor,
                                                      const int* __restrict__ cvbase,
                                                      int* __restrict__ rowptr,
                                                      int2* __restrict__ cv, int nrows) {
    __shared__ int hcnt[1024], sa[1024], sb[1024], rcur[1024];
    __shared__ int2 buf[LDSE];
    int b = blockIdx.x;
    int cnt = (int)(cursor[b] >> 32);
    int cvb = cvbase[b];
    const int2* stage = arena + (size_t)b * ARENA_S;
    int nr = 1 << BSHIFT;
    int rb = b << BSHIFT;
    for (int i = threadIdx.x; i < nr; i += 256) hcnt[i] = 0;
    __syncthreads();
    bool fits = (cnt <= LDSE);
    if (fits) {
        for (int i = threadIdx.x; i < cnt; i += 256) {
            int2 e = stage[i];
            buf[i] = e;
            atomicAdd(&hcnt[(unsigned)e.x >> 22], 1);
        }
    } else {
        for (int i = threadIdx.x; i < cnt; i += 256)
            atomicAdd(&hcnt[(unsigned)stage[i].x >> 22], 1);
    }
    __syncthreads();
    for (int i = threadIdx.x; i < nr; i += 256) sa[i] = hcnt[i];
    __syncthreads();
    int* curp = sa; int* nxtp = sb;
    for (int off = 1; off < nr; off <<= 1) {
        for (int i = threadIdx.x; i < nr; i += 256)
            nxtp[i] = (i >= off) ? curp[i - off] + curp[i] : curp[i];
        __syncthreads();
        int* t = curp; curp = nxtp; nxtp = t;
    }
    for (int i = threadIdx.x; i < nr; i += 256) {
        int excl = curp[i] - hcnt[i];
        rcur[i] = excl;
        int row = rb + i;
        if (row < nrows) rowptr[row] = cvb + excl;
    }
    __syncthreads();
    if (fits) {
        for (int i = threadIdx.x; i < cnt; i += 256) {
            int2 e = buf[i];
            int rl = (unsigned)e.x >> 22;
            int pos = atomicAdd(&rcur[rl], 1);
            cv[cvb + pos] = make_int2(e.x & 0x3FFFFF, e.y);
        }
    } else {
        for (int i = threadIdx.x; i < cnt; i += 256) {
            int2 e = stage[i];
            int rl = (unsigned)e.x >> 22;
            int pos = atomicAdd(&rcur[rl], 1);
            cv[cvb + pos] = make_int2(e.x & 0x3FFFFF, e.y);
        }
    }
}

// ---------- layer-0 unified gather (act cols -> XWbuf slots) ----------
// no min-waves clause (round-10: forcing 8 waves/SIMD spills q[8] -> scratch traffic)
__global__ __launch_bounds__(256) void gather0_kernel(
    const int* __restrict__ rp, const int2* __restrict__ cv,
    const __half* __restrict__ XW, __half* __restrict__ act, int nrows) {
    int row = (blockIdx.x * 256 + threadIdx.x) >> 2;
    int j = threadIdx.x & 3;
    if (row >= nrows) return;
    int rank = (row >= AB2) ? 2 : ((row >= AB1) ? 1 : 0);
    int t1 = (rank == 2) ? AB2 : AB1;
    int t2 = (rank == 1) ? AB2 : IMAXC;
    int off0 = (rank == 0) ? (XB0 - AB0) : ((rank == 1) ? (XB4 - AB0) : (XB6 - AB1));
    int off1 = (rank == 0) ? (XB5 - AB1) : ((rank == 1) ? (XB1 - AB1) : (XB2 - AB2));
    int off2 = (rank == 1) ? (XB3 - AB2) : 0;
    float scale = (rank == 1) ? (1.f / 3.f) : 0.5f;
    int ks = rp[row], ke = rp[row + 1];
    float s[8] = { 0.f, 0.f, 0.f, 0.f, 0.f, 0.f, 0.f, 0.f };
    for (int k = ks; k < ke; k += 8) {
        int2 e[8];
#pragma unroll
        for (int u = 0; u < 8; ++u) {
            int kk = k + u;
            e[u] = cv[(kk < ke) ? kk : (ke - 1)];
        }
        uint4 q[8];
#pragma unroll
        for (int u = 0; u < 8; ++u) {
            int c = e[u].x;
            int add = (c < t1) ? off0 : ((c < t2) ? off1 : off2);
            q[u] = *(const uint4*)(XW + (size_t)(c + add) * 32 + j * 8);
        }
#pragma unroll
        for (int u = 0; u < 8; ++u) {
            float v = (k + u < ke) ? __int_as_float(e[u].y) : 0.f;
            const unsigned* qq = &q[u].x;
#pragma unroll
            for (int h = 0; h < 4; ++h) {
                float2 f2 = __half22float2(*(__half2*)&qq[h]);
                s[2 * h] = fmaf(v, f2.x, s[2 * h]);
                s[2 * h + 1] = fmaf(v, f2.y, s[2 * h + 1]);
            }
        }
    }
    uint4 ov;
    unsigned* op = &ov.x;
#pragma unroll
    for (int h = 0; h < 4; ++h) {
        __half2 o2 = __floats2half2_rn(fmaxf(s[2 * h], 0.f) * scale,
                                       fmaxf(s[2 * h + 1], 0.f) * scale);
        op[h] = *(unsigned*)&o2;
    }
    *(uint4*)(act + (size_t)row * 32 + j * 8) = ov;
}

// ---------- layers 1..3 unified fused gather+W ----------
__global__ __launch_bounds__(256) void ugw_kernel(
    const int* __restrict__ rp, const int2* __restrict__ cv,
    const __half* __restrict__ actin, __half* __restrict__ actout,
    const float* __restrict__ Wl, int tile0, int ntiles) {
    int gid = (blockIdx.x * 256 + threadIdx.x) >> 6;
    if (gid >= ntiles) return;
    gid += tile0;
    int lane = threadIdx.x & 63;
    int li = lane & 15;
    int lk = lane >> 4;
    int rbase = gid << 4;
    int rank = (rbase >= AB2) ? 2 : ((rbase >= AB1) ? 1 : 0);
    int t1 = (rank == 2) ? AB2 : AB1;
    int t2 = (rank == 1) ? AB2 : IMAXC;
    float scale = (rank == 1) ? (1.f / 3.f) : 0.5f;
    int wk0 = (rank == 0) ? 0 : ((rank == 1) ? 1 : 4);
    int wk1 = (rank == 0) ? 3 : ((rank == 1) ? 2 : 6);
    int wk2 = (rank == 1) ? 5 : 0;
    const float* Wa = Wl + (size_t)wk0 * 1024;
    const float* Wb = Wl + (size_t)wk1 * 1024;
    const float* Wc = Wl + (size_t)wk2 * 1024;
    int row = rbase + li;
    int ks = rp[row], ke = rp[row + 1];
    float acc[3][8];
#pragma unroll
    for (int m = 0; m < 3; ++m)
#pragma unroll
        for (int d = 0; d < 8; ++d) acc[m][d] = 0.f;
    for (int k = ks; k < ke; k += 8) {
        int2 e[8];
#pragma unroll
        for (int u = 0; u < 8; ++u) {
            int kk = k + u;
            e[u] = cv[(kk < ke) ? kk : (ke - 1)];
        }
        uint4 q[8];
#pragma unroll
        for (int u = 0; u < 8; ++u)
            q[u] = *(const uint4*)(actin + (size_t)e[u].x * 32 + lk * 8);
#pragma unroll
        for (int u = 0; u < 8; ++u) {
            float bv = (k + u < ke) ? __int_as_float(e[u].y) : 0.f;
            int c = e[u].x;
            float s0 = (c < t1) ? bv : 0.f;
            float s2 = (c >= t2) ? bv : 0.f;
            float s1 = bv - s0 - s2;
            const unsigned* qq = &q[u].x;
#pragma unroll
            for (int h = 0; h < 4; ++h) {
                float2 f2 = __half22float2(*(__half2*)&qq[h]);
                acc[0][2 * h] = fmaf(s0, f2.x, acc[0][2 * h]);
                acc[0][2 * h + 1] = fmaf(s0, f2.y, acc[0][2 * h + 1]);
                acc[1][2 * h] = fmaf(s1, f2.x, acc[1][2 * h]);
                acc[1][2 * h + 1] = fmaf(s1, f2.y, acc[1][2 * h + 1]);
                acc[2][2 * h] = fmaf(s2, f2.x, acc[2][2 * h]);
                acc[2][2 * h + 1] = fmaf(s2, f2.y, acc[2][2 * h + 1]);
            }
        }
    }
    const float* Ws[3] = { Wa, Wb, Wc };
    f32x4 d0 = { 0.f, 0.f, 0.f, 0.f };
    f32x4 d1 = { 0.f, 0.f, 0.f, 0.f };
#pragma unroll
    for (int m = 0; m < 3; ++m) {
        half8 a, b0, b1;
#pragma unroll
        for (int r = 0; r < 8; ++r) {
            a[r] = (_Float16)acc[m][r];
            int kk = lk * 8 + r;
            b0[r] = (_Float16)Ws[m][kk * 32 + li];
            b1[r] = (_Float16)Ws[m][kk * 32 + 16 + li];
        }
        d0 = __builtin_amdgcn_mfma_f32_16x16x32_f16(a, b0, d0, 0, 0, 0);
        d1 = __builtin_amdgcn_mfma_f32_16x16x32_f16(a, b1, d1, 0, 0, 0);
    }
#pragma unroll
    for (int r = 0; r < 4; ++r) {
        size_t orow = (size_t)(rbase + lk * 4 + r);
        actout[orow * 32 + li] = __float2half(fmaxf(d0[r], 0.f) * scale);
        actout[orow * 32 + 16 + li] = __float2half(fmaxf(d1[r], 0.f) * scale);
    }
}

// ---------- pooling ----------
#define BPG 4
__global__ __launch_bounds__(256) void pool_kernel(const __half* __restrict__ x1,
                                                   const int* __restrict__ batch,
                                                   float* __restrict__ sums,
                                                   float* __restrict__ cnt, int n) {
    __shared__ float red[256][8];
    int g = blockIdx.x / BPG;
    int p = blockIdx.x % BPG;
    int lo = 0, hi = n;
    while (lo < hi) { int mid = (lo + hi) >> 1; if (batch[mid] < g) lo = mid + 1; else hi = mid; }
    int s0 = lo;
    lo = s0; hi = n;
    while (lo < hi) { int mid = (lo + hi) >> 1; if (batch[mid] < g + 1) lo = mid + 1; else hi = mid; }
    int s1 = lo;
    int tid = threadIdx.x;
    int qr = tid & 3;
    int rt = tid >> 2;
    float acc[8] = { 0.f, 0.f, 0.f, 0.f, 0.f, 0.f, 0.f, 0.f };
    for (int r = s0 + p * 64 + rt; r < s1; r += BPG * 64) {
        half8 v = *(const half8*)(x1 + (size_t)r * 32 + qr * 8);
#pragma unroll
        for (int u = 0; u < 8; ++u) acc[u] += fabsf((float)v[u]);
    }
#pragma unroll
    for (int u = 0; u < 8; ++u) red[tid][u] = acc[u];
    __syncthreads();
    for (int off = 128; off >= 4; off >>= 1) {
        if (tid < off) {
#pragma unroll
            for (int u = 0; u < 8; ++u) red[tid][u] += red[tid + off][u];
        }
        __syncthreads();
    }
    if (tid < 4) {
#pragma unroll
        for (int u = 0; u < 8; ++u)
            atomicAdd(&sums[(size_t)g * D + tid * 8 + u], red[tid][u]);
    }
    if (p == 0 && tid == 0) cnt[g] = (float)(s1 - s0);
}

// ---------- head ----------
__global__ void head_kernel(const float* __restrict__ sums, const float* __restrict__ cnt,
                            const float* __restrict__ w1, const float* __restrict__ b1,
                            const float* __restrict__ w2, const float* __restrict__ b2,
                            float* __restrict__ out) {
    __shared__ float W1s[D * D], W2s[D * 10], B1s[D], B2s[10];
    int tid = threadIdx.x;
    for (int i = tid; i < D * D; i += blockDim.x) W1s[i] = w1[i];
    for (int i = tid; i < D * 10; i += blockDim.x) W2s[i] = w2[i];
    if (tid < D) B1s[tid] = b1[tid];
    if (tid < 10) B2s[tid] = b2[tid];
    __syncthreads();
    int g = tid;
    if (g >= NGC) return;
    float invc = 1.f / fmaxf(cnt[g], 1.f);
    float p[D];
#pragma unroll
    for (int k = 0; k < D; ++k) p[k] = sums[(size_t)g * D + k] * invc;
    float h[D];
#pragma unroll
    for (int j = 0; j < D; ++j) {
        float s = B1s[j];
#pragma unroll
        for (int k = 0; k < D; ++k) s = fmaf(p[k], W1s[k * D + j], s);
        h[j] = fmaxf(s, 0.f);
    }
    float l[10];
    float m = -1e30f;
#pragma unroll
    for (int o = 0; o < 10; ++o) {
        float s = B2s[o];
#pragma unroll
        for (int k = 0; k < D; ++k) s = fmaf(h[k], W2s[k * 10 + o], s);
        l[o] = s;
        m = fmaxf(m, s);
    }
    float den = 0.f;
#pragma unroll
    for (int o = 0; o < 10; ++o) { l[o] = expf(l[o] - m); den += l[o]; }
    float inv = 1.f / den;
#pragma unroll
    for (int o = 0; o < 10; ++o) out[g * 10 + o] = l[o] * inv;
}

extern "C" void kernel_launch(void* const* d_in, const int* in_sizes, int n_in,
                              void* d_out, int out_size, void* d_ws, size_t ws_size,
                              hipStream_t stream) {
    const float* X0 = (const float*)d_in[0];
    const float* X1 = (const float*)d_in[1];
    const float* X2 = (const float*)d_in[2];
    // mats: 0=L0,1=L1,2=L2,3=B2D3,4=D2B1TD1inv,5=D1invB1,6=B2TD2inv
    const int* spr[7]; const int* spc[7]; const float* spv[7]; int spn[7];
    for (int m = 0; m < 7; ++m) {
        spr[m] = (const int*)d_in[3 + m * 3];
        spc[m] = (const int*)d_in[4 + m * 3];
        spv[m] = (const float*)d_in[5 + m * 3];
        spn[m] = in_sizes[3 + m * 3];
    }
    const int* batch1 = (const int*)d_in[24];
    const float* W1 = (const float*)d_in[25];
    const float* W234 = (const float*)d_in[26];
    const float* mlp1_w = (const float*)d_in[27];
    const float* mlp1_b = (const float*)d_in[28];
    const float* mlp2_w = (const float*)d_in[29];
    const float* mlp2_b = (const float*)d_in[30];
    float* out = (float*)d_out;

    const int rowbase_mat[7] = { AB0, AB1, AB2, AB1, AB1, AB0, AB2 };
    const int colbase_mat[7] = { AB0, AB1, AB2, AB2, AB0, AB1, AB1 };
    const int XWROWS = 3000000;

    // ---- workspace carve (proven r17/18 footprint ~553MB; all 64B-aligned) ----
#define ALIGN64(p) ((char*)(((size_t)(p) + 63) & ~(size_t)63))
    char* wp = (char*)d_ws;
    __half* actA = (__half*)wp;            wp = ALIGN64(wp + (size_t)NRC * 32 * sizeof(__half));
    __half* XWbuf = (__half*)wp;           wp = ALIGN64(wp + (size_t)XWROWS * 32 * sizeof(__half));
    __half* actB = XWbuf;                  // aliases XWbuf (XWbuf dead after gather0)
    size_t total_nnz = 0;
    for (int m = 0; m < 7; ++m) total_nnz += (size_t)spn[m];
    int2* cv_base = (int2*)wp;             wp = ALIGN64(wp + total_nnz * sizeof(int2));
    int2* arena = (int2*)wp;               wp = ALIGN64(wp + (size_t)NBUK * ARENA_S * sizeof(int2)); // 145.2MB
    int* rowptr = (int*)wp;                wp = ALIGN64(wp + (size_t)(NRC + 3) * sizeof(int));
    u64* cursor = (u64*)wp;                wp = ALIGN64(wp + (size_t)(NBUK + 4) * sizeof(u64));
    int* cvbase = (int*)wp;                wp = ALIGN64(wp + (size_t)(NBUK + 4) * sizeof(int));
    float* sums = (float*)wp;              wp = ALIGN64(wp + (size_t)NGC * D * sizeof(float));
    float* cnt = (float*)wp;               wp = ALIGN64(wp + (size_t)NGC * sizeof(float));
#undef ALIGN64

    // ---- fused build + layer-0 xw ----
    int ncht = 0;
    {
        BuildArgs A;
        for (int m = 0; m < 7; ++m) {
            A.rows[m] = spr[m];
            A.cols[m] = spc[m];
            A.vals[m] = spv[m];
            A.nnz[m] = spn[m];
            A.rbase[m] = rowbase_mat[m];
            A.cbase[m] = colbase_mat[m];
            A.cstart[m] = ncht;
            ncht += (spn[m] + CHUNKE - 1) / CHUNKE;
        }
        A.cstart[7] = ncht;
        A.ncht = ncht;
        A.xs[0] = X0; A.xs[1] = X1; A.xs[2] = X2;
        const size_t wst = (size_t)64 * 32;
        A.Wp[0] = W1 + 0 * wst; A.Op[0] = XWbuf + (size_t)XB0 * 32;
        A.Wp[1] = W1 + 1 * wst; A.Op[1] = XWbuf + (size_t)XB4 * 32;
        A.Wp[2] = W1 + 0 * wst; A.Op[2] = nullptr;
        A.Wp[3] = W1 + 2 * wst; A.Op[3] = XWbuf + (size_t)XB1 * 32;
        A.Wp[4] = W1 + 3 * wst; A.Op[4] = XWbuf + (size_t)XB5 * 32;
        A.Wp[5] = W1 + 4 * wst; A.Op[5] = XWbuf + (size_t)XB6 * 32;
        A.Wp[6] = W1 + 6 * wst; A.Op[6] = XWbuf + (size_t)XB2 * 32;
        A.Wp[7] = W1 + 5 * wst; A.Op[7] = XWbuf + (size_t)XB3 * 32;
        A.Wp[8] = W1 + 6 * wst; A.Op[8] = nullptr;
        A.nS[0] = N0C; A.nS[1] = N1C; A.nS[2] = N2C;
        A.nmS[0] = 2; A.nmS[1] = 3; A.nmS[2] = 2;
        A.xb0[0] = 0; A.xb0[1] = 512; A.xb0[2] = 1536;
        A.xnb[0] = 512; A.xnb[1] = 1024; A.xnb[2] = 512;

        cursor_init_kernel<<<(NBUK + 255) / 256, 256, 0, stream>>>(cursor);
        ubin_xw_kernel<<<ncht + GXW, 256, 0, stream>>>(A, cursor, arena);
        scan_counts_kernel<<<1, 256, 0, stream>>>(cursor, cvbase);
        binsort_kernel<<<NBUK, 256, 0, stream>>>(arena, cursor, cvbase, rowptr,
                                                 cv_base, NRC);
        set_final_kernel<<<1, 1, 0, stream>>>(rowptr + NRC, (int)total_nnz);
    }

    // ---- layer 0 gather (xw done inside the fused dispatch) ----
    gather0_kernel<<<(int)(((size_t)NRC * 4 + 255) / 256), 256, 0, stream>>>(
        rowptr, cv_base, XWbuf, actA, NRC);

    // ---- layers 1..3: one unified gather+W dispatch each ----
    for (int l = 1; l < 4; ++l) {
        const float* Wl = W234 + (size_t)(l - 1) * 7 * 32 * 32;
        const __half* src = (l & 1) ? actA : actB;
        __half* dst = (l & 1) ? actB : actA;
        if (l < 3) {
            int ntiles = NRC / 16;
            ugw_kernel<<<(ntiles + 3) / 4, 256, 0, stream>>>(
                rowptr, cv_base, src, dst, Wl, 0, ntiles);
        } else {
            int ntiles = N1C / 16;
            ugw_kernel<<<(ntiles + 3) / 4, 256, 0, stream>>>(
                rowptr, cv_base, src, dst, Wl, AB1 / 16, ntiles);
        }
    }

    hipMemsetAsync(sums, 0, (size_t)(NGC * D + NGC) * sizeof(float), stream);
    pool_kernel<<<NGC * BPG, 256, 0, stream>>>(actB + (size_t)AB1 * 32, batch1, sums, cnt, N1C);
    head_kernel<<<1, 128, 0, stream>>>(sums, cnt, mlp1_w, mlp1_b, mlp2_w, mlp2_b, out);
}

// Round 23
// 1797.453 us; speedup vs baseline: 1.0805x; 1.0236x over previous
//
#include <hip/hip_runtime.h>
#include <hip/hip_fp16.h>

#define N0C 200000
#define N1C 600000
#define N2C 400000
#define NRC (N0C + N1C + N2C)
#define NGC 128
#define D 32
#define CHUNKE 32768
#define BSHIFT 10
#define NBUK ((NRC + 1023) >> 10)   // 1172
#define ARENA_S 15488               // mean 14334 + >8 sigma; 64B-aligned (*8B)
#define LDSE 15360
#define GXW 2048                    // xw blocks appended to the build dispatch

#define AB0 0
#define AB1 N0C
#define AB2 (N0C + N1C)
#define IMAXC 0x7fffffff

// XWbuf slot bases (layer-0 projections)
#define XB0 0
#define XB1 200000
#define XB2 800000
#define XB3 1200000
#define XB4 1600000
#define XB5 1800000
#define XB6 2400000

typedef __attribute__((ext_vector_type(8))) _Float16 half8;
typedef __attribute__((ext_vector_type(4))) float f32x4;

struct BuildArgs {
    // binning
    const int* rows[7];
    const int* cols[7];
    const float* vals[7];
    int nnz[7];
    int cstart[8];
    int rbase[7];
    int cbase[7];
    int ncht;
    // layer-0 xw (DIN=64, fp32 sources)
    const float* xs[3];
    const float* Wp[9];   // [src*3 + m]
    __half* Op[9];        // [src*3 + m], null = skip store
    int nS[3];
    int nmS[3];
    int xb0[3];           // xw block-range base per src
    int xnb[3];           // xw block-range size per src
};

// ---------- init ----------
__global__ void cursor_init_kernel(int* __restrict__ cursor) {
    int b = blockIdx.x * blockDim.x + threadIdx.x;
    if (b < NBUK) cursor[b] = b * ARENA_S;
}

// ---------- fused: [0,ncht) bin blocks ; [ncht, ncht+GXW) layer-0 xw blocks ----------
__global__ __launch_bounds__(256) void ubin_xw_kernel(BuildArgs A, int* __restrict__ cursor,
                                                      int2* __restrict__ arena) {
    __shared__ int hcnt[NBUK];
    __shared__ int wcur[NBUK];
    int bid = blockIdx.x;
    if (bid < A.ncht) {
        // ---------------- binning path ----------------
        int m = 0;
        while (bid >= A.cstart[m + 1]) ++m;
        int base = (bid - A.cstart[m]) * CHUNKE;
        const int* rows = A.rows[m];
        const int* cols = A.cols[m];
        const float* vals = A.vals[m];
        int nnz = A.nnz[m];
        int rb = A.rbase[m];
        int cb = A.cbase[m];
        for (int i = threadIdx.x; i < NBUK; i += 256) hcnt[i] = 0;
        __syncthreads();
        for (int i = threadIdx.x; i < CHUNKE; i += 256) {
            int e = base + i;
            if (e < nnz) atomicAdd(&hcnt[(rows[e] + rb) >> BSHIFT], 1);
        }
        __syncthreads();
        for (int b = threadIdx.x; b < NBUK; b += 256) {
            int c = hcnt[b];
            wcur[b] = c ? atomicAdd(&cursor[b], c) : 0;
        }
        __syncthreads();
        for (int i = threadIdx.x; i < CHUNKE; i += 256) {
            int e = base + i;
            if (e < nnz) {
                int r = rows[e] + rb;
                int b = r >> BSHIFT;
                int rl = r & ((1 << BSHIFT) - 1);
                int pos = atomicAdd(&wcur[b], 1);
                arena[pos] = make_int2((rl << 22) | (cols[e] + cb), __float_as_int(vals[e]));
            }
        }
        return;
    }
    // ---------------- layer-0 xw path (DIN=64, F32 src) ----------------
    int xwid = bid - A.ncht;
    int s = (xwid >= A.xb0[2]) ? 2 : ((xwid >= A.xb0[1]) ? 1 : 0);
    int tbase = xwid - A.xb0[s];
    int tstride = A.xnb[s];
    const float* xsrc = A.xs[s];
    int n = A.nS[s];
    int nm = A.nmS[s];
    const float* W0 = A.Wp[s * 3 + 0];
    const float* W1p = A.Wp[s * 3 + 1];
    const float* W2p = (nm > 2) ? A.Wp[s * 3 + 2] : A.Wp[s * 3 + 0];
    __half* O0 = A.Op[s * 3 + 0];
    __half* O1 = A.Op[s * 3 + 1];
    __half* O2 = (nm > 2) ? A.Op[s * 3 + 2] : nullptr;
    const float* Ws[3] = { W0, W1p, W2p };
    __half* Os[3] = { O0, O1, O2 };

    int wave = (tbase * 256 + (int)threadIdx.x) >> 6;
    int nwaves = tstride * 4;
    int lane = threadIdx.x & 63;
    int li = lane & 15;
    int lk = lane >> 4;
    half8 bfrag[3][2][2];
#pragma unroll
    for (int m = 0; m < 3; ++m)
#pragma unroll
        for (int ct = 0; ct < 2; ++ct)
#pragma unroll
            for (int ks = 0; ks < 2; ++ks)
#pragma unroll
                for (int r = 0; r < 8; ++r) {
                    int k = ks * 32 + lk * 8 + r;
                    int j = ct * 16 + li;
                    bfrag[m][ct][ks][r] = (_Float16)Ws[m][k * 32 + j];
                }
    int ntiles = (n + 15) >> 4;
    for (int t = wave; t < ntiles; t += nwaves) {
        int rbase = t << 4;
        int arow = rbase + li;
        int arowc = (arow < n) ? arow : (n - 1);
        half8 afrag[2];
#pragma unroll
        for (int ks = 0; ks < 2; ++ks) {
            const float* p = xsrc + (size_t)arowc * 64 + ks * 32 + lk * 8;
            float4 u = *(const float4*)p;
            float4 v = *(const float4*)(p + 4);
            afrag[ks] = (half8){ (_Float16)u.x, (_Float16)u.y, (_Float16)u.z, (_Float16)u.w,
                                 (_Float16)v.x, (_Float16)v.y, (_Float16)v.z, (_Float16)v.w };
        }
#pragma unroll
        for (int m = 0; m < 3; ++m) {
            if (!Os[m]) continue;
#pragma unroll
            for (int ct = 0; ct < 2; ++ct) {
                f32x4 acc = { 0.f, 0.f, 0.f, 0.f };
#pragma unroll
                for (int ks = 0; ks < 2; ++ks)
                    acc = __builtin_amdgcn_mfma_f32_16x16x32_f16(afrag[ks], bfrag[m][ct][ks],
                                                                 acc, 0, 0, 0);
#pragma unroll
                for (int r = 0; r < 4; ++r) {
                    int row = rbase + lk * 4 + r;
                    if (row < n)
                        Os[m][(size_t)row * 32 + ct * 16 + li] = __float2half(acc[r]);
                }
            }
        }
    }
}

// ---------- parallel exclusive scan of bucket counts (from cursor deltas) ----------
__global__ __launch_bounds__(256) void scan_counts_kernel(const int* __restrict__ cursor,
                                                          int* __restrict__ cvbase) {
    __shared__ int part[256];
    int t = threadIdx.x;
    int s = 0;
    int v[8];
#pragma unroll
    for (int u = 0; u < 8; ++u) {
        int b = t * 8 + u;
        int c = (b < NBUK) ? (cursor[b] - b * ARENA_S) : 0;
        v[u] = s;
        s += c;
    }
    part[t] = s;
    __syncthreads();
    if (t == 0) {
        int acc = 0;
        for (int i = 0; i < 256; ++i) { int q = part[i]; part[i] = acc; acc += q; }
    }
    __syncthreads();
    int off = part[t];
#pragma unroll
    for (int u = 0; u < 8; ++u) {
        int b = t * 8 + u;
        if (b <= NBUK) cvbase[b] = off + v[u];
    }
    if (t == 255) cvbase[NBUK] = off + s;
}

__global__ void set_final_kernel(int* __restrict__ dst, int v) { *dst = v; }

// ---------- per-bucket LDS counting sort (1024 rows) ----------
__global__ __launch_bounds__(256) void binsort_kernel(const int2* __restrict__ arena,
                                                      const int* __restrict__ cursor,
                                                      const int* __restrict__ cvbase,
                                                      int* __restrict__ rowptr,
                                                      int2* __restrict__ cv, int nrows) {
    __shared__ int hcnt[1024], sa[1024], sb[1024], rcur[1024];
    __shared__ int2 buf[LDSE];
    int b = blockIdx.x;
    int cnt = cursor[b] - b * ARENA_S;
    int cvb = cvbase[b];
    const int2* stage = arena + (size_t)b * ARENA_S;
    int nr = 1 << BSHIFT;
    int rb = b << BSHIFT;
    for (int i = threadIdx.x; i < nr; i += 256) hcnt[i] = 0;
    __syncthreads();
    for (int i = threadIdx.x; i < cnt; i += 256)
        atomicAdd(&hcnt[(unsigned)stage[i].x >> 22], 1);
    __syncthreads();
    for (int i = threadIdx.x; i < nr; i += 256) sa[i] = hcnt[i];
    __syncthreads();
    int* curp = sa; int* nxtp = sb;
    for (int off = 1; off < nr; off <<= 1) {
        for (int i = threadIdx.x; i < nr; i += 256)
            nxtp[i] = (i >= off) ? curp[i - off] + curp[i] : curp[i];
        __syncthreads();
        int* t = curp; curp = nxtp; nxtp = t;
    }
    for (int i = threadIdx.x; i < nr; i += 256) {
        int excl = curp[i] - hcnt[i];
        rcur[i] = excl;
        int row = rb + i;
        if (row < nrows) rowptr[row] = cvb + excl;
    }
    __syncthreads();
    if (cnt <= LDSE) {
        for (int i = threadIdx.x; i < cnt; i += 256) {
            int2 e = stage[i];
            int rl = (unsigned)e.x >> 22;
            int pos = atomicAdd(&rcur[rl], 1);
            buf[pos] = make_int2(e.x & 0x3FFFFF, e.y);
        }
        __syncthreads();
        for (int i = threadIdx.x; i < cnt; i += 256)
            cv[cvb + i] = buf[i];
    } else {
        for (int i = threadIdx.x; i < cnt; i += 256) {
            int2 e = stage[i];
            int rl = (unsigned)e.x >> 22;
            int pos = atomicAdd(&rcur[rl], 1);
            cv[cvb + pos] = make_int2(e.x & 0x3FFFFF, e.y);
        }
    }
}

// ---------- layer-0 unified gather (act cols -> XWbuf slots) ----------
// no min-waves clause (round-10: forcing 8 waves/SIMD spills q[8] -> scratch traffic)
__global__ __launch_bounds__(256) void gather0_kernel(
    const int* __restrict__ rp, const int2* __restrict__ cv,
    const __half* __restrict__ XW, __half* __restrict__ act, int nrows) {
    int row = (blockIdx.x * 256 + threadIdx.x) >> 2;
    int j = threadIdx.x & 3;
    if (row >= nrows) return;
    int rank = (row >= AB2) ? 2 : ((row >= AB1) ? 1 : 0);
    int t1 = (rank == 2) ? AB2 : AB1;
    int t2 = (rank == 1) ? AB2 : IMAXC;
    int off0 = (rank == 0) ? (XB0 - AB0) : ((rank == 1) ? (XB4 - AB0) : (XB6 - AB1));
    int off1 = (rank == 0) ? (XB5 - AB1) : ((rank == 1) ? (XB1 - AB1) : (XB2 - AB2));
    int off2 = (rank == 1) ? (XB3 - AB2) : 0;
    float scale = (rank == 1) ? (1.f / 3.f) : 0.5f;
    int ks = rp[row], ke = rp[row + 1];
    float s[8] = { 0.f, 0.f, 0.f, 0.f, 0.f, 0.f, 0.f, 0.f };
    for (int k = ks; k < ke; k += 8) {
        int2 e[8];
#pragma unroll
        for (int u = 0; u < 8; ++u) {
            int kk = k + u;
            e[u] = cv[(kk < ke) ? kk : (ke - 1)];
        }
        uint4 q[8];
#pragma unroll
        for (int u = 0; u < 8; ++u) {
            int c = e[u].x;
            int add = (c < t1) ? off0 : ((c < t2) ? off1 : off2);
            q[u] = *(const uint4*)(XW + (size_t)(c + add) * 32 + j * 8);
        }
#pragma unroll
        for (int u = 0; u < 8; ++u) {
            float v = (k + u < ke) ? __int_as_float(e[u].y) : 0.f;
            const unsigned* qq = &q[u].x;
#pragma unroll
            for (int h = 0; h < 4; ++h) {
                float2 f2 = __half22float2(*(__half2*)&qq[h]);
                s[2 * h] = fmaf(v, f2.x, s[2 * h]);
                s[2 * h + 1] = fmaf(v, f2.y, s[2 * h + 1]);
            }
        }
    }
    uint4 ov;
    unsigned* op = &ov.x;
#pragma unroll
    for (int h = 0; h < 4; ++h) {
        __half2 o2 = __floats2half2_rn(fmaxf(s[2 * h], 0.f) * scale,
                                       fmaxf(s[2 * h + 1], 0.f) * scale);
        op[h] = *(unsigned*)&o2;
    }
    *(uint4*)(act + (size_t)row * 32 + j * 8) = ov;
}

// ---------- layers 1..3 unified fused gather+W ----------
__global__ __launch_bounds__(256) void ugw_kernel(
    const int* __restrict__ rp, const int2* __restrict__ cv,
    const __half* __restrict__ actin, __half* __restrict__ actout,
    const float* __restrict__ Wl, int tile0, int ntiles) {
    int gid = (blockIdx.x * 256 + threadIdx.x) >> 6;
    if (gid >= ntiles) return;
    gid += tile0;
    int lane = threadIdx.x & 63;
    int li = lane & 15;
    int lk = lane >> 4;
    int rbase = gid << 4;
    int rank = (rbase >= AB2) ? 2 : ((rbase >= AB1) ? 1 : 0);
    int t1 = (rank == 2) ? AB2 : AB1;
    int t2 = (rank == 1) ? AB2 : IMAXC;
    float scale = (rank == 1) ? (1.f / 3.f) : 0.5f;
    int wk0 = (rank == 0) ? 0 : ((rank == 1) ? 1 : 4);
    int wk1 = (rank == 0) ? 3 : ((rank == 1) ? 2 : 6);
    int wk2 = (rank == 1) ? 5 : 0;
    const float* Wa = Wl + (size_t)wk0 * 1024;
    const float* Wb = Wl + (size_t)wk1 * 1024;
    const float* Wc = Wl + (size_t)wk2 * 1024;
    int row = rbase + li;
    int ks = rp[row], ke = rp[row + 1];
    float acc[3][8];
#pragma unroll
    for (int m = 0; m < 3; ++m)
#pragma unroll
        for (int d = 0; d < 8; ++d) acc[m][d] = 0.f;
    for (int k = ks; k < ke; k += 8) {
        int2 e[8];
#pragma unroll
        for (int u = 0; u < 8; ++u) {
            int kk = k + u;
            e[u] = cv[(kk < ke) ? kk : (ke - 1)];
        }
        uint4 q[8];
#pragma unroll
        for (int u = 0; u < 8; ++u)
            q[u] = *(const uint4*)(actin + (size_t)e[u].x * 32 + lk * 8);
#pragma unroll
        for (int u = 0; u < 8; ++u) {
            float bv = (k + u < ke) ? __int_as_float(e[u].y) : 0.f;
            int c = e[u].x;
            float s0 = (c < t1) ? bv : 0.f;
            float s2 = (c >= t2) ? bv : 0.f;
            float s1 = bv - s0 - s2;
            const unsigned* qq = &q[u].x;
#pragma unroll
            for (int h = 0; h < 4; ++h) {
                float2 f2 = __half22float2(*(__half2*)&qq[h]);
                acc[0][2 * h] = fmaf(s0, f2.x, acc[0][2 * h]);
                acc[0][2 * h + 1] = fmaf(s0, f2.y, acc[0][2 * h + 1]);
                acc[1][2 * h] = fmaf(s1, f2.x, acc[1][2 * h]);
                acc[1][2 * h + 1] = fmaf(s1, f2.y, acc[1][2 * h + 1]);
                acc[2][2 * h] = fmaf(s2, f2.x, acc[2][2 * h]);
                acc[2][2 * h + 1] = fmaf(s2, f2.y, acc[2][2 * h + 1]);
            }
        }
    }
    const float* Ws[3] = { Wa, Wb, Wc };
    f32x4 d0 = { 0.f, 0.f, 0.f, 0.f };
    f32x4 d1 = { 0.f, 0.f, 0.f, 0.f };
#pragma unroll
    for (int m = 0; m < 3; ++m) {
        half8 a, b0, b1;
#pragma unroll
        for (int r = 0; r < 8; ++r) {
            a[r] = (_Float16)acc[m][r];
            int kk = lk * 8 + r;
            b0[r] = (_Float16)Ws[m][kk * 32 + li];
            b1[r] = (_Float16)Ws[m][kk * 32 + 16 + li];
        }
        d0 = __builtin_amdgcn_mfma_f32_16x16x32_f16(a, b0, d0, 0, 0, 0);
        d1 = __builtin_amdgcn_mfma_f32_16x16x32_f16(a, b1, d1, 0, 0, 0);
    }
#pragma unroll
    for (int r = 0; r < 4; ++r) {
        size_t orow = (size_t)(rbase + lk * 4 + r);
        actout[orow * 32 + li] = __float2half(fmaxf(d0[r], 0.f) * scale);
        actout[orow * 32 + 16 + li] = __float2half(fmaxf(d1[r], 0.f) * scale);
    }
}

// ---------- pooling ----------
#define BPG 4
__global__ __launch_bounds__(256) void pool_kernel(const __half* __restrict__ x1,
                                                   const int* __restrict__ batch,
                                                   float* __restrict__ sums,
                                                   float* __restrict__ cnt, int n) {
    __shared__ float red[256][8];
    int g = blockIdx.x / BPG;
    int p = blockIdx.x % BPG;
    int lo = 0, hi = n;
    while (lo < hi) { int mid = (lo + hi) >> 1; if (batch[mid] < g) lo = mid + 1; else hi = mid; }
    int s0 = lo;
    lo = s0; hi = n;
    while (lo < hi) { int mid = (lo + hi) >> 1; if (batch[mid] < g + 1) lo = mid + 1; else hi = mid; }
    int s1 = lo;
    int tid = threadIdx.x;
    int qr = tid & 3;
    int rt = tid >> 2;
    float acc[8] = { 0.f, 0.f, 0.f, 0.f, 0.f, 0.f, 0.f, 0.f };
    for (int r = s0 + p * 64 + rt; r < s1; r += BPG * 64) {
        half8 v = *(const half8*)(x1 + (size_t)r * 32 + qr * 8);
#pragma unroll
        for (int u = 0; u < 8; ++u) acc[u] += fabsf((float)v[u]);
    }
#pragma unroll
    for (int u = 0; u < 8; ++u) red[tid][u] = acc[u];
    __syncthreads();
    for (int off = 128; off >= 4; off >>= 1) {
        if (tid < off) {
#pragma unroll
            for (int u = 0; u < 8; ++u) red[tid][u] += red[tid + off][u];
        }
        __syncthreads();
    }
    if (tid < 4) {
#pragma unroll
        for (int u = 0; u < 8; ++u)
            atomicAdd(&sums[(size_t)g * D + tid * 8 + u], red[tid][u]);
    }
    if (p == 0 && tid == 0) cnt[g] = (float)(s1 - s0);
}

// ---------- head ----------
__global__ void head_kernel(const float* __restrict__ sums, const float* __restrict__ cnt,
                            const float* __restrict__ w1, const float* __restrict__ b1,
                            const float* __restrict__ w2, const float* __restrict__ b2,
                            float* __restrict__ out) {
    __shared__ float W1s[D * D], W2s[D * 10], B1s[D], B2s[10];
    int tid = threadIdx.x;
    for (int i = tid; i < D * D; i += blockDim.x) W1s[i] = w1[i];
    for (int i = tid; i < D * 10; i += blockDim.x) W2s[i] = w2[i];
    if (tid < D) B1s[tid] = b1[tid];
    if (tid < 10) B2s[tid] = b2[tid];
    __syncthreads();
    int g = tid;
    if (g >= NGC) return;
    float invc = 1.f / fmaxf(cnt[g], 1.f);
    float p[D];
#pragma unroll
    for (int k = 0; k < D; ++k) p[k] = sums[(size_t)g * D + k] * invc;
    float h[D];
#pragma unroll
    for (int j = 0; j < D; ++j) {
        float s = B1s[j];
#pragma unroll
        for (int k = 0; k < D; ++k) s = fmaf(p[k], W1s[k * D + j], s);
        h[j] = fmaxf(s, 0.f);
    }
    float l[10];
    float m = -1e30f;
#pragma unroll
    for (int o = 0; o < 10; ++o) {
        float s = B2s[o];
#pragma unroll
        for (int k = 0; k < D; ++k) s = fmaf(h[k], W2s[k * 10 + o], s);
        l[o] = s;
        m = fmaxf(m, s);
    }
    float den = 0.f;
#pragma unroll
    for (int o = 0; o < 10; ++o) { l[o] = expf(l[o] - m); den += l[o]; }
    float inv = 1.f / den;
#pragma unroll
    for (int o = 0; o < 10; ++o) out[g * 10 + o] = l[o] * inv;
}

extern "C" void kernel_launch(void* const* d_in, const int* in_sizes, int n_in,
                              void* d_out, int out_size, void* d_ws, size_t ws_size,
                              hipStream_t stream) {
    const float* X0 = (const float*)d_in[0];
    const float* X1 = (const float*)d_in[1];
    const float* X2 = (const float*)d_in[2];
    // mats: 0=L0,1=L1,2=L2,3=B2D3,4=D2B1TD1inv,5=D1invB1,6=B2TD2inv
    const int* spr[7]; const int* spc[7]; const float* spv[7]; int spn[7];
    for (int m = 0; m < 7; ++m) {
        spr[m] = (const int*)d_in[3 + m * 3];
        spc[m] = (const int*)d_in[4 + m * 3];
        spv[m] = (const float*)d_in[5 + m * 3];
        spn[m] = in_sizes[3 + m * 3];
    }
    const int* batch1 = (const int*)d_in[24];
    const float* W1 = (const float*)d_in[25];
    const float* W234 = (const float*)d_in[26];
    const float* mlp1_w = (const float*)d_in[27];
    const float* mlp1_b = (const float*)d_in[28];
    const float* mlp2_w = (const float*)d_in[29];
    const float* mlp2_b = (const float*)d_in[30];
    float* out = (float*)d_out;

    const int rowbase_mat[7] = { AB0, AB1, AB2, AB1, AB1, AB0, AB2 };
    const int colbase_mat[7] = { AB0, AB1, AB2, AB2, AB0, AB1, AB1 };
    const int XWROWS = 3000000;

    // ---- workspace carve (r17-proven footprint; all 64B-aligned) ----
#define ALIGN64(p) ((char*)(((size_t)(p) + 63) & ~(size_t)63))
    char* wp = (char*)d_ws;
    __half* actA = (__half*)wp;            wp = ALIGN64(wp + (size_t)NRC * 32 * sizeof(__half));
    __half* XWbuf = (__half*)wp;           wp = ALIGN64(wp + (size_t)XWROWS * 32 * sizeof(__half));
    __half* actB = XWbuf;                  // aliases XWbuf (XWbuf dead after gather0)
    size_t total_nnz = 0;
    for (int m = 0; m < 7; ++m) total_nnz += (size_t)spn[m];
    int2* cv_base = (int2*)wp;             wp = ALIGN64(wp + total_nnz * sizeof(int2));
    int2* arena = (int2*)wp;               wp = ALIGN64(wp + (size_t)NBUK * ARENA_S * sizeof(int2));
    int* rowptr = (int*)wp;                wp = ALIGN64(wp + (size_t)(NRC + 3) * sizeof(int));
    int* cursor = (int*)wp;                wp = ALIGN64(wp + (size_t)(NBUK + 4) * sizeof(int));
    int* cvbase = (int*)wp;                wp = ALIGN64(wp + (size_t)(NBUK + 4) * sizeof(int));
    float* sums = (float*)wp;              wp = ALIGN64(wp + (size_t)NGC * D * sizeof(float));
    float* cnt = (float*)wp;               wp = ALIGN64(wp + (size_t)NGC * sizeof(float));
#undef ALIGN64

    // ---- fused build + layer-0 xw (independent work overlapped via block split) ----
    int ncht = 0;
    {
        BuildArgs A;
        for (int m = 0; m < 7; ++m) {
            A.rows[m] = spr[m];
            A.cols[m] = spc[m];
            A.vals[m] = spv[m];
            A.nnz[m] = spn[m];
            A.rbase[m] = rowbase_mat[m];
            A.cbase[m] = colbase_mat[m];
            A.cstart[m] = ncht;
            ncht += (spn[m] + CHUNKE - 1) / CHUNKE;
        }
        A.cstart[7] = ncht;
        A.ncht = ncht;
        A.xs[0] = X0; A.xs[1] = X1; A.xs[2] = X2;
        const size_t wst = (size_t)64 * 32;
        // x0 -> {W0->XB0, W1->XB4}; x1 -> {W2->XB1, W3->XB5, W4->XB6}; x2 -> {W6->XB2, W5->XB3}
        A.Wp[0] = W1 + 0 * wst; A.Op[0] = XWbuf + (size_t)XB0 * 32;
        A.Wp[1] = W1 + 1 * wst; A.Op[1] = XWbuf + (size_t)XB4 * 32;
        A.Wp[2] = W1 + 0 * wst; A.Op[2] = nullptr;
        A.Wp[3] = W1 + 2 * wst; A.Op[3] = XWbuf + (size_t)XB1 * 32;
        A.Wp[4] = W1 + 3 * wst; A.Op[4] = XWbuf + (size_t)XB5 * 32;
        A.Wp[5] = W1 + 4 * wst; A.Op[5] = XWbuf + (size_t)XB6 * 32;
        A.Wp[6] = W1 + 6 * wst; A.Op[6] = XWbuf + (size_t)XB2 * 32;
        A.Wp[7] = W1 + 5 * wst; A.Op[7] = XWbuf + (size_t)XB3 * 32;
        A.Wp[8] = W1 + 6 * wst; A.Op[8] = nullptr;
        A.nS[0] = N0C; A.nS[1] = N1C; A.nS[2] = N2C;
        A.nmS[0] = 2; A.nmS[1] = 3; A.nmS[2] = 2;
        A.xb0[0] = 0; A.xb0[1] = 512; A.xb0[2] = 1536;
        A.xnb[0] = 512; A.xnb[1] = 1024; A.xnb[2] = 512;

        cursor_init_kernel<<<(NBUK + 255) / 256, 256, 0, stream>>>(cursor);
        ubin_xw_kernel<<<ncht + GXW, 256, 0, stream>>>(A, cursor, arena);
        scan_counts_kernel<<<1, 256, 0, stream>>>(cursor, cvbase);
        binsort_kernel<<<NBUK, 256, 0, stream>>>(arena, cursor, cvbase, rowptr,
                                                 cv_base, NRC);
        set_final_kernel<<<1, 1, 0, stream>>>(rowptr + NRC, (int)total_nnz);
    }

    // ---- layer 0 gather (xw already done inside the fused dispatch) ----
    gather0_kernel<<<(int)(((size_t)NRC * 4 + 255) / 256), 256, 0, stream>>>(
        rowptr, cv_base, XWbuf, actA, NRC);

    // ---- layers 1..3: one unified gather+W dispatch each ----
    for (int l = 1; l < 4; ++l) {
        const float* Wl = W234 + (size_t)(l - 1) * 7 * 32 * 32;
        const __half* src = (l & 1) ? actA : actB;
        __half* dst = (l & 1) ? actB : actA;
        if (l < 3) {
            int ntiles = NRC / 16;
            ugw_kernel<<<(ntiles + 3) / 4, 256, 0, stream>>>(
                rowptr, cv_base, src, dst, Wl, 0, ntiles);
        } else {
            int ntiles = N1C / 16;
            ugw_kernel<<<(ntiles + 3) / 4, 256, 0, stream>>>(
                rowptr, cv_base, src, dst, Wl, AB1 / 16, ntiles);
        }
    }

    hipMemsetAsync(sums, 0, (size_t)(NGC * D + NGC) * sizeof(float), stream);
    pool_kernel<<<NGC * BPG, 256, 0, stream>>>(actB + (size_t)AB1 * 32, batch1, sums, cnt, N1C);
    head_kernel<<<1, 128, 0, stream>>>(sums, cnt, mlp1_w, mlp1_b, mlp2_w, mlp2_b, out);
}